// Round 3
// baseline (414.939 us; speedup 1.0000x reference)
//
#include <hip/hip_runtime.h>
#include <hip/hip_bf16.h>
#include <math.h>

#define BATCH 65536
#define DIM 256
#define KC 1024
#define COMMIT 0.25f
#define DECAY 0.99f
#define EPSV 1e-5f

// Output layout (floats, concatenated in reference return order)
#define O_ZQ   0                       // 65536*256
#define O_LOSS 16777216                // 1
#define O_PERP 16777217                // 1
#define O_IDX  16777218                // 65536 (indices written as float values)
#define O_EMB  16842754                // 1024*256 new_embedding
#define O_NCS  17104898                // 1024 new_ema_cluster_size
#define O_NEW  17105922                // 1024*256 new_ema_w

typedef __attribute__((ext_vector_type(8))) short bf16x8;
typedef __attribute__((ext_vector_type(4))) float f32x4;

__device__ __forceinline__ unsigned short bf16_rne(float x) {
    unsigned u = __builtin_bit_cast(unsigned, x);
    unsigned r = (u + 0x7FFFu + ((u >> 16) & 1u)) >> 16;
    return (unsigned short)r;
}
__device__ __forceinline__ float bf16_to_f(unsigned short h) {
    unsigned u = ((unsigned)h) << 16;
    return __builtin_bit_cast(float, u);
}

// ---------------- zero small accumulators ----------------------------------
__global__ __launch_bounds__(256) void zero_kernel(int* __restrict__ counts,
                                                   float* __restrict__ loss_part) {
    int i = blockIdx.x * 256 + threadIdx.x;
    if (i < KC) counts[i] = 0;
    if (i < 256) loss_part[i] = 0.0f;
}

// ---------------- emb -> bf16 hi/lo split + e_sq ---------------------------
__global__ __launch_bounds__(64) void prep_kernel(const float* __restrict__ emb,
                                                  unsigned short* __restrict__ ehi,
                                                  unsigned short* __restrict__ elo,
                                                  float* __restrict__ e_sq) {
    int k = blockIdx.x;
    int lane = threadIdx.x;
    const float4* ep = (const float4*)(emb + (size_t)k * DIM);
    float4 e = ep[lane];
    float x[4] = {e.x, e.y, e.z, e.w};
    unsigned h[4], l[4];
    float s = 0.0f;
    #pragma unroll
    for (int j = 0; j < 4; ++j) {
        h[j] = bf16_rne(x[j]);
        l[j] = bf16_rne(x[j] - bf16_to_f((unsigned short)h[j]));
        s += x[j] * x[j];
    }
    uint2 ph = make_uint2(h[0] | (h[1] << 16), h[2] | (h[3] << 16));
    uint2 pl = make_uint2(l[0] | (l[1] << 16), l[2] | (l[3] << 16));
    ((uint2*)(ehi + (size_t)k * DIM))[lane] = ph;
    ((uint2*)(elo + (size_t)k * DIM))[lane] = pl;
    for (int off = 32; off; off >>= 1) s += __shfl_down(s, off, 64);
    if (lane == 0) e_sq[k] = s;
}

// ---------------- MFMA distance + argmin -----------------------------------
#define CH_ROWS 64
#define ROW_US 264   /* 264 ushorts = 528 B padded row stride */
__global__ __launch_bounds__(256, 2) void argmin_kernel(
        const float* __restrict__ z_e,
        const unsigned short* __restrict__ ehi,
        const unsigned short* __restrict__ elo,
        const float* __restrict__ e_sq,
        int* __restrict__ idx_out, float* __restrict__ idx_f_out) {
    __shared__ __align__(16) unsigned short bhi_s[CH_ROWS * ROW_US];
    __shared__ __align__(16) unsigned short blo_s[CH_ROWS * ROW_US];
    __shared__ float esq_s[KC];

    int tid = threadIdx.x;
    int w = tid >> 6;
    int lane = tid & 63;
    int m16 = lane & 15;
    int quad = lane >> 4;
    int base_m = blockIdx.x * 128 + w * 32;

    #pragma unroll
    for (int i = 0; i < 4; ++i) esq_s[tid + i * 256] = e_sq[tid + i * 256];

    // load + split A fragments: A[m=lane&15][k=quad*8+j]
    bf16x8 ahi[2][8], alo[2][8];
    #pragma unroll
    for (int f = 0; f < 2; ++f) {
        const float* zr = z_e + (size_t)(base_m + f * 16 + m16) * DIM;
        #pragma unroll
        for (int ks = 0; ks < 8; ++ks) {
            const float4* p = (const float4*)(zr + ks * 32 + quad * 8);
            float4 x0 = p[0], x1 = p[1];
            float xs[8] = {x0.x, x0.y, x0.z, x0.w, x1.x, x1.y, x1.z, x1.w};
            #pragma unroll
            for (int j = 0; j < 8; ++j) {
                unsigned short h = bf16_rne(xs[j]);
                unsigned short l = bf16_rne(xs[j] - bf16_to_f(h));
                ahi[f][ks][j] = (short)h;
                alo[f][ks][j] = (short)l;
            }
        }
    }

    float best0[4] = {1e30f, 1e30f, 1e30f, 1e30f};
    float best1[4] = {1e30f, 1e30f, 1e30f, 1e30f};
    int bk0[4] = {0, 0, 0, 0};
    int bk1[4] = {0, 0, 0, 0};

    for (int chunk = 0; chunk < 16; ++chunk) {
        __syncthreads();
        const int4* gh = (const int4*)(ehi + (size_t)chunk * CH_ROWS * DIM);
        const int4* gl = (const int4*)(elo + (size_t)chunk * CH_ROWS * DIM);
        #pragma unroll
        for (int i = 0; i < 8; ++i) {
            int c = tid + i * 256;
            int r = c >> 5;
            int col = c & 31;
            int4 vh = gh[c];
            int4 vl = gl[c];
            *(int4*)((char*)bhi_s + r * 528 + col * 16) = vh;
            *(int4*)((char*)blo_s + r * 528 + col * 16) = vl;
        }
        __syncthreads();

        #pragma unroll
        for (int f = 0; f < 4; ++f) {
            f32x4 acc0 = {0.f, 0.f, 0.f, 0.f};
            f32x4 acc1 = {0.f, 0.f, 0.f, 0.f};
            const unsigned short* bh_base = bhi_s + (f * 16 + m16) * ROW_US + quad * 8;
            const unsigned short* bl_base = blo_s + (f * 16 + m16) * ROW_US + quad * 8;
            #pragma unroll
            for (int ks = 0; ks < 8; ++ks) {
                bf16x8 bh = *(const bf16x8*)(bh_base + ks * 32);
                bf16x8 bl = *(const bf16x8*)(bl_base + ks * 32);
                acc0 = __builtin_amdgcn_mfma_f32_16x16x32_bf16(ahi[0][ks], bh, acc0, 0, 0, 0);
                acc1 = __builtin_amdgcn_mfma_f32_16x16x32_bf16(ahi[1][ks], bh, acc1, 0, 0, 0);
                acc0 = __builtin_amdgcn_mfma_f32_16x16x32_bf16(ahi[0][ks], bl, acc0, 0, 0, 0);
                acc1 = __builtin_amdgcn_mfma_f32_16x16x32_bf16(ahi[1][ks], bl, acc1, 0, 0, 0);
                acc0 = __builtin_amdgcn_mfma_f32_16x16x32_bf16(alo[0][ks], bh, acc0, 0, 0, 0);
                acc1 = __builtin_amdgcn_mfma_f32_16x16x32_bf16(alo[1][ks], bh, acc1, 0, 0, 0);
            }
            int col = chunk * 64 + f * 16 + m16;
            float es = esq_s[col];
            #pragma unroll
            for (int r = 0; r < 4; ++r) {
                float d0 = es - 2.0f * acc0[r];
                float d1 = es - 2.0f * acc1[r];
                if (d0 < best0[r]) { best0[r] = d0; bk0[r] = col; }
                if (d1 < best1[r]) { best1[r] = d1; bk1[r] = col; }
            }
        }
    }

    #pragma unroll
    for (int off = 1; off < 16; off <<= 1) {
        #pragma unroll
        for (int r = 0; r < 4; ++r) {
            float ov0 = __shfl_xor(best0[r], off, 64);
            int   ok0 = __shfl_xor(bk0[r], off, 64);
            if (ov0 < best0[r] || (ov0 == best0[r] && ok0 < bk0[r])) { best0[r] = ov0; bk0[r] = ok0; }
            float ov1 = __shfl_xor(best1[r], off, 64);
            int   ok1 = __shfl_xor(bk1[r], off, 64);
            if (ov1 < best1[r] || (ov1 == best1[r] && ok1 < bk1[r])) { best1[r] = ov1; bk1[r] = ok1; }
        }
    }
    if (m16 == 0) {
        #pragma unroll
        for (int r = 0; r < 4; ++r) {
            int row0 = base_m + quad * 4 + r;
            int row1 = base_m + 16 + quad * 4 + r;
            idx_out[row0] = bk0[r];
            idx_f_out[row0] = (float)bk0[r];
            idx_out[row1] = bk1[r];
            idx_f_out[row1] = (float)bk1[r];
        }
    }
}

// ---------------- z_q gather + loss (streaming, one wave per row) -----------
__global__ __launch_bounds__(256) void zq_loss_kernel(
        const float* __restrict__ z_e, const float* __restrict__ emb,
        const int* __restrict__ idx, float* __restrict__ zq_out,
        float* __restrict__ loss_part) {
    int gid = blockIdx.x * 256 + threadIdx.x;
    int row = gid >> 6;
    int lane = gid & 63;
    int k = idx[row];   // wave-uniform broadcast
    float4 z = ((const float4*)(z_e + (size_t)row * DIM))[lane];
    float4 q = ((const float4*)(emb + (size_t)k * DIM))[lane];
    float4 o;
    o.x = z.x + (q.x - z.x);
    o.y = z.y + (q.y - z.y);
    o.z = z.z + (q.z - z.z);
    o.w = z.w + (q.w - z.w);
    ((float4*)(zq_out + (size_t)row * DIM))[lane] = o;
    float dx = q.x - z.x, dy = q.y - z.y, dz = q.z - z.z, dwv = q.w - z.w;
    float ls = dx * dx + dy * dy + dz * dz + dwv * dwv;
    for (int off = 32; off; off >>= 1) ls += __shfl_down(ls, off, 64);
    __shared__ float red[4];
    if (lane == 0) red[threadIdx.x >> 6] = ls;
    __syncthreads();
    if (threadIdx.x == 0)
        atomicAdd(&loss_part[blockIdx.x & 255], red[0] + red[1] + red[2] + red[3]);
}

// ---------------- histogram of indices (= cluster_size) ---------------------
__global__ __launch_bounds__(256) void hist_kernel(const int* __restrict__ idx,
                                                   int* __restrict__ counts) {
    __shared__ int h[KC];
    int t = threadIdx.x;
    #pragma unroll
    for (int i = t; i < KC; i += 256) h[i] = 0;
    __syncthreads();
    int base = blockIdx.x * (BATCH / 128);
    #pragma unroll
    for (int i = t; i < BATCH / 128; i += 256) atomicAdd(&h[idx[base + i]], 1);
    __syncthreads();
    #pragma unroll
    for (int i = t; i < KC; i += 256) if (h[i]) atomicAdd(&counts[i], h[i]);
}

// ---------------- exclusive prefix scan over counts -------------------------
__global__ __launch_bounds__(1024) void prefix_kernel(const int* __restrict__ counts,
                                                      int* __restrict__ starts,
                                                      int* __restrict__ cursor) {
    __shared__ int sc[KC];
    int t = threadIdx.x;
    int c = counts[t];
    sc[t] = c;
    __syncthreads();
    for (int off = 1; off < KC; off <<= 1) {
        int v = 0;
        if (t >= off) v = sc[t - off];
        __syncthreads();
        if (t >= off) sc[t] += v;
        __syncthreads();
    }
    int ex = sc[t] - c;
    starts[t] = ex;
    cursor[t] = ex;
    if (t == KC - 1) starts[KC] = sc[t];
}

// ---------------- bucket rows by cluster ------------------------------------
__global__ __launch_bounds__(256) void scatter_rows_kernel(
        const int* __restrict__ idx, int* __restrict__ cursor,
        int* __restrict__ sorted_rows) {
    int i = blockIdx.x * 256 + threadIdx.x;
    int k = idx[i];
    int pos = atomicAdd(&cursor[k], 1);
    sorted_rows[pos] = i;
}

// ---------------- dw[k][d] = sum of z rows in cluster k (no atomics) --------
__global__ __launch_bounds__(256) void dw_kernel(
        const float* __restrict__ z_e, const int* __restrict__ starts,
        const int* __restrict__ sorted_rows, float* __restrict__ dw) {
    __shared__ int rows_s[256];
    int k = blockIdx.x;
    int t = threadIdx.x;
    int start = starts[k], end = starts[k + 1];
    float acc = 0.0f;
    for (int cs = start; cs < end; cs += 256) {
        int n = end - cs; if (n > 256) n = 256;
        __syncthreads();
        if (t < n) rows_s[t] = sorted_rows[cs + t];
        __syncthreads();
        for (int i = 0; i < n; ++i)
            acc += z_e[(size_t)rows_s[i] * DIM + t];
    }
    dw[(size_t)k * DIM + t] = acc;
}

// ---------------- per-cluster EMA, n, perplexity, loss ----------------------
__global__ __launch_bounds__(1024) void finalize_cluster(
        const float* __restrict__ ema_cs, const int* __restrict__ counts,
        const float* __restrict__ loss_part, float* __restrict__ out,
        float* __restrict__ n_ws) {
    __shared__ float s1[1024];
    __shared__ float s2[1024];
    __shared__ float s3[1024];
    int t = threadIdx.x;
    float c = (float)counts[t];
    float ncs = DECAY * ema_cs[t] + (1.0f - DECAY) * c;
    out[O_NCS + t] = ncs;
    float p = c / (float)BATCH;
    s1[t] = ncs;
    s2[t] = p * logf(p + 1e-10f);
    s3[t] = (t < 256) ? loss_part[t] : 0.0f;
    __syncthreads();
    for (int s = 512; s; s >>= 1) {
        if (t < s) { s1[t] += s1[t + s]; s2[t] += s2[t + s]; s3[t] += s3[t + s]; }
        __syncthreads();
    }
    if (t == 0) {
        n_ws[0] = s1[0];
        out[O_PERP] = expf(-s2[0]);
        out[O_LOSS] = COMMIT * s3[0] / (float)((size_t)BATCH * DIM);
    }
}

// ---------------- new_ema_w and new_embedding -------------------------------
__global__ __launch_bounds__(256) void finalize_emb(
        const float* __restrict__ ema_w, const float* __restrict__ dw,
        const float* __restrict__ ncs_arr, const float* __restrict__ n_ws,
        float* __restrict__ out_emb, float* __restrict__ out_emaw) {
    int k = blockIdx.x;
    int d = threadIdx.x;
    size_t i = (size_t)k * DIM + d;
    float w = DECAY * ema_w[i] + (1.0f - DECAY) * dw[i];
    out_emaw[i] = w;
    float n = n_ws[0];
    float ncs = ncs_arr[k];
    float smoothed = (ncs + EPSV) / (n + (float)KC * EPSV) * n;
    out_emb[i] = w / smoothed;
}

extern "C" void kernel_launch(void* const* d_in, const int* in_sizes, int n_in,
                              void* d_out, int out_size, void* d_ws, size_t ws_size,
                              hipStream_t stream) {
    const float* z_e    = (const float*)d_in[0];
    const float* emb    = (const float*)d_in[1];
    const float* ema_cs = (const float*)d_in[2];
    const float* ema_w  = (const float*)d_in[3];
    float* out = (float*)d_out;
    float* ws = (float*)d_ws;

    // workspace layout (16B-aligned chunks first)
    float* dw            = ws;                                   // 262144 f
    unsigned short* ehi  = (unsigned short*)(dw + KC * DIM);     // 262144 us
    unsigned short* elo  = ehi + KC * DIM;                       // 262144 us
    float* e_sq          = (float*)(elo + KC * DIM);             // 1024 f
    int* idx             = (int*)(e_sq + KC);                    // 65536 i
    int* counts          = idx + BATCH;                          // 1024 i
    int* starts          = counts + KC;                          // 1025 i
    int* cursor          = starts + KC + 1;                      // 1024 i
    int* sorted_rows     = cursor + KC;                          // 65536 i
    float* loss_part     = (float*)(sorted_rows + BATCH);        // 256 f
    float* n_ws          = loss_part + 256;                      // 1 f

    zero_kernel<<<dim3(4), dim3(256), 0, stream>>>(counts, loss_part);
    prep_kernel<<<dim3(KC), dim3(64), 0, stream>>>(emb, ehi, elo, e_sq);
    argmin_kernel<<<dim3(BATCH / 128), dim3(256), 0, stream>>>(
        z_e, ehi, elo, e_sq, idx, out + O_IDX);
    zq_loss_kernel<<<dim3(BATCH * 64 / 256), dim3(256), 0, stream>>>(
        z_e, emb, idx, out + O_ZQ, loss_part);
    hist_kernel<<<dim3(128), dim3(256), 0, stream>>>(idx, counts);
    prefix_kernel<<<dim3(1), dim3(1024), 0, stream>>>(counts, starts, cursor);
    scatter_rows_kernel<<<dim3(BATCH / 256), dim3(256), 0, stream>>>(
        idx, cursor, sorted_rows);
    dw_kernel<<<dim3(KC), dim3(256), 0, stream>>>(z_e, starts, sorted_rows, dw);
    finalize_cluster<<<dim3(1), dim3(1024), 0, stream>>>(
        ema_cs, counts, loss_part, out, n_ws);
    finalize_emb<<<dim3(KC), dim3(256), 0, stream>>>(
        ema_w, dw, out + O_NCS, n_ws, out + O_EMB, out + O_NEW);
}

// Round 4
// 283.655 us; speedup vs baseline: 1.4628x; 1.4628x over previous
//
#include <hip/hip_runtime.h>
#include <hip/hip_bf16.h>
#include <math.h>

#define BATCH 65536
#define DIM 256
#define KC 1024
#define COMMIT 0.25f
#define DECAY 0.99f
#define EPSV 1e-5f

// Output layout (floats, concatenated in reference return order)
#define O_ZQ   0                       // 65536*256
#define O_LOSS 16777216                // 1
#define O_PERP 16777217                // 1
#define O_IDX  16777218                // 65536 (indices written as float values)
#define O_EMB  16842754                // 1024*256 new_embedding
#define O_NCS  17104898                // 1024 new_ema_cluster_size
#define O_NEW  17105922                // 1024*256 new_ema_w

typedef __attribute__((ext_vector_type(8))) short bf16x8;
typedef __attribute__((ext_vector_type(4))) float f32x4;

__device__ __forceinline__ unsigned short bf16_rne(float x) {
    unsigned u = __builtin_bit_cast(unsigned, x);
    unsigned r = (u + 0x7FFFu + ((u >> 16) & 1u)) >> 16;
    return (unsigned short)r;
}
__device__ __forceinline__ float bf16_to_f(unsigned short h) {
    unsigned u = ((unsigned)h) << 16;
    return __builtin_bit_cast(float, u);
}

// ---------------- zero accumulators (dw needs zeros for atomic flushes) -----
__global__ __launch_bounds__(256) void zero_kernel(float* __restrict__ dw,
                                                   int* __restrict__ counts,
                                                   float* __restrict__ loss_part) {
    int i = blockIdx.x * 256 + threadIdx.x;
    if (i < KC * DIM) dw[i] = 0.0f;
    if (i < KC) counts[i] = 0;
    if (i < 256) loss_part[i] = 0.0f;
}

// ---------------- emb -> bf16 hi/lo split + e_sq ---------------------------
__global__ __launch_bounds__(64) void prep_kernel(const float* __restrict__ emb,
                                                  unsigned short* __restrict__ ehi,
                                                  unsigned short* __restrict__ elo,
                                                  float* __restrict__ e_sq) {
    int k = blockIdx.x;
    int lane = threadIdx.x;
    const float4* ep = (const float4*)(emb + (size_t)k * DIM);
    float4 e = ep[lane];
    float x[4] = {e.x, e.y, e.z, e.w};
    unsigned h[4], l[4];
    float s = 0.0f;
    #pragma unroll
    for (int j = 0; j < 4; ++j) {
        h[j] = bf16_rne(x[j]);
        l[j] = bf16_rne(x[j] - bf16_to_f((unsigned short)h[j]));
        s += x[j] * x[j];
    }
    uint2 ph = make_uint2(h[0] | (h[1] << 16), h[2] | (h[3] << 16));
    uint2 pl = make_uint2(l[0] | (l[1] << 16), l[2] | (l[3] << 16));
    ((uint2*)(ehi + (size_t)k * DIM))[lane] = ph;
    ((uint2*)(elo + (size_t)k * DIM))[lane] = pl;
    for (int off = 32; off; off >>= 1) s += __shfl_down(s, off, 64);
    if (lane == 0) e_sq[k] = s;
}

// ---------------- MFMA distance + argmin -----------------------------------
#define CH_ROWS 64
#define ROW_US 264   /* 264 ushorts = 528 B padded row stride */
__global__ __launch_bounds__(256, 2) void argmin_kernel(
        const float* __restrict__ z_e,
        const unsigned short* __restrict__ ehi,
        const unsigned short* __restrict__ elo,
        const float* __restrict__ e_sq,
        int* __restrict__ idx_out, float* __restrict__ idx_f_out) {
    __shared__ __align__(16) unsigned short bhi_s[CH_ROWS * ROW_US];
    __shared__ __align__(16) unsigned short blo_s[CH_ROWS * ROW_US];
    __shared__ float esq_s[KC];

    int tid = threadIdx.x;
    int w = tid >> 6;
    int lane = tid & 63;
    int m16 = lane & 15;
    int quad = lane >> 4;
    int base_m = blockIdx.x * 128 + w * 32;

    #pragma unroll
    for (int i = 0; i < 4; ++i) esq_s[tid + i * 256] = e_sq[tid + i * 256];

    // load + split A fragments: A[m=lane&15][k=quad*8+j]
    bf16x8 ahi[2][8], alo[2][8];
    #pragma unroll
    for (int f = 0; f < 2; ++f) {
        const float* zr = z_e + (size_t)(base_m + f * 16 + m16) * DIM;
        #pragma unroll
        for (int ks = 0; ks < 8; ++ks) {
            const float4* p = (const float4*)(zr + ks * 32 + quad * 8);
            float4 x0 = p[0], x1 = p[1];
            float xs[8] = {x0.x, x0.y, x0.z, x0.w, x1.x, x1.y, x1.z, x1.w};
            #pragma unroll
            for (int j = 0; j < 8; ++j) {
                unsigned short h = bf16_rne(xs[j]);
                unsigned short l = bf16_rne(xs[j] - bf16_to_f(h));
                ahi[f][ks][j] = (short)h;
                alo[f][ks][j] = (short)l;
            }
        }
    }

    float best0[4] = {1e30f, 1e30f, 1e30f, 1e30f};
    float best1[4] = {1e30f, 1e30f, 1e30f, 1e30f};
    int bk0[4] = {0, 0, 0, 0};
    int bk1[4] = {0, 0, 0, 0};

    for (int chunk = 0; chunk < 16; ++chunk) {
        __syncthreads();
        const int4* gh = (const int4*)(ehi + (size_t)chunk * CH_ROWS * DIM);
        const int4* gl = (const int4*)(elo + (size_t)chunk * CH_ROWS * DIM);
        #pragma unroll
        for (int i = 0; i < 8; ++i) {
            int c = tid + i * 256;
            int r = c >> 5;
            int col = c & 31;
            int4 vh = gh[c];
            int4 vl = gl[c];
            *(int4*)((char*)bhi_s + r * 528 + col * 16) = vh;
            *(int4*)((char*)blo_s + r * 528 + col * 16) = vl;
        }
        __syncthreads();

        #pragma unroll
        for (int f = 0; f < 4; ++f) {
            f32x4 acc0 = {0.f, 0.f, 0.f, 0.f};
            f32x4 acc1 = {0.f, 0.f, 0.f, 0.f};
            const unsigned short* bh_base = bhi_s + (f * 16 + m16) * ROW_US + quad * 8;
            const unsigned short* bl_base = blo_s + (f * 16 + m16) * ROW_US + quad * 8;
            #pragma unroll
            for (int ks = 0; ks < 8; ++ks) {
                bf16x8 bh = *(const bf16x8*)(bh_base + ks * 32);
                bf16x8 bl = *(const bf16x8*)(bl_base + ks * 32);
                acc0 = __builtin_amdgcn_mfma_f32_16x16x32_bf16(ahi[0][ks], bh, acc0, 0, 0, 0);
                acc1 = __builtin_amdgcn_mfma_f32_16x16x32_bf16(ahi[1][ks], bh, acc1, 0, 0, 0);
                acc0 = __builtin_amdgcn_mfma_f32_16x16x32_bf16(ahi[0][ks], bl, acc0, 0, 0, 0);
                acc1 = __builtin_amdgcn_mfma_f32_16x16x32_bf16(ahi[1][ks], bl, acc1, 0, 0, 0);
                acc0 = __builtin_amdgcn_mfma_f32_16x16x32_bf16(alo[0][ks], bh, acc0, 0, 0, 0);
                acc1 = __builtin_amdgcn_mfma_f32_16x16x32_bf16(alo[1][ks], bh, acc1, 0, 0, 0);
            }
            int col = chunk * 64 + f * 16 + m16;
            float es = esq_s[col];
            #pragma unroll
            for (int r = 0; r < 4; ++r) {
                float d0 = es - 2.0f * acc0[r];
                float d1 = es - 2.0f * acc1[r];
                if (d0 < best0[r]) { best0[r] = d0; bk0[r] = col; }
                if (d1 < best1[r]) { best1[r] = d1; bk1[r] = col; }
            }
        }
    }

    #pragma unroll
    for (int off = 1; off < 16; off <<= 1) {
        #pragma unroll
        for (int r = 0; r < 4; ++r) {
            float ov0 = __shfl_xor(best0[r], off, 64);
            int   ok0 = __shfl_xor(bk0[r], off, 64);
            if (ov0 < best0[r] || (ov0 == best0[r] && ok0 < bk0[r])) { best0[r] = ov0; bk0[r] = ok0; }
            float ov1 = __shfl_xor(best1[r], off, 64);
            int   ok1 = __shfl_xor(bk1[r], off, 64);
            if (ov1 < best1[r] || (ov1 == best1[r] && ok1 < bk1[r])) { best1[r] = ov1; bk1[r] = ok1; }
        }
    }
    if (m16 == 0) {
        #pragma unroll
        for (int r = 0; r < 4; ++r) {
            int row0 = base_m + quad * 4 + r;
            int row1 = base_m + 16 + quad * 4 + r;
            idx_out[row0] = bk0[r];
            idx_f_out[row0] = (float)bk0[r];
            idx_out[row1] = bk1[r];
            idx_f_out[row1] = (float)bk1[r];
        }
    }
}

// ---------------- histogram of indices (= cluster_size) ---------------------
__global__ __launch_bounds__(256) void hist_kernel(const int* __restrict__ idx,
                                                   int* __restrict__ counts) {
    __shared__ int h[KC];
    int t = threadIdx.x;
    #pragma unroll
    for (int i = t; i < KC; i += 256) h[i] = 0;
    __syncthreads();
    int base = blockIdx.x * (BATCH / 128);
    #pragma unroll
    for (int i = t; i < BATCH / 128; i += 256) atomicAdd(&h[idx[base + i]], 1);
    __syncthreads();
    #pragma unroll
    for (int i = t; i < KC; i += 256) if (h[i]) atomicAdd(&counts[i], h[i]);
}

// ---------------- exclusive prefix scan over counts -------------------------
__global__ __launch_bounds__(1024) void prefix_kernel(const int* __restrict__ counts,
                                                      int* __restrict__ cursor) {
    __shared__ int sc[KC];
    int t = threadIdx.x;
    int c = counts[t];
    sc[t] = c;
    __syncthreads();
    for (int off = 1; off < KC; off <<= 1) {
        int v = 0;
        if (t >= off) v = sc[t - off];
        __syncthreads();
        if (t >= off) sc[t] += v;
        __syncthreads();
    }
    cursor[t] = sc[t] - c;
}

// ---------------- bucket rows by cluster ------------------------------------
__global__ __launch_bounds__(256) void scatter_rows_kernel(
        const int* __restrict__ idx, int* __restrict__ cursor,
        int* __restrict__ sorted_rows) {
    int i = blockIdx.x * 256 + threadIdx.x;
    int k = idx[i];
    int pos = atomicAdd(&cursor[k], 1);
    sorted_rows[pos] = i;
}

// ---------------- fused: z_q gather + loss + dw (balanced 64-row segments) --
// 1024 blocks x 256 thr; block b owns sorted positions [b*64, b*64+64).
// Cluster key is wave-uniform; running acc flushed via atomicAdd on key change
// (~2 flushes/block avg). Every block does identical work -> no imbalance tail.
#define SEG 64
__global__ __launch_bounds__(256) void dw_zq_kernel(
        const float* __restrict__ z_e, const float* __restrict__ emb,
        const int* __restrict__ idx, const int* __restrict__ sorted_rows,
        float* __restrict__ zq_out, float* __restrict__ dw,
        float* __restrict__ loss_part) {
    __shared__ int rows_s[SEG];
    __shared__ int keys_s[SEG];
    int t = threadIdx.x;
    int base = blockIdx.x * SEG;
    if (t < SEG) {
        int r = sorted_rows[base + t];
        rows_s[t] = r;
        keys_s[t] = idx[r];
    }
    __syncthreads();

    float acc = 0.0f;
    float lsum = 0.0f;
    int kprev = keys_s[0];
    for (int i = 0; i < SEG; ++i) {
        int row = rows_s[i];
        int k = keys_s[i];
        float z = z_e[(size_t)row * DIM + t];
        float q = emb[(size_t)k * DIM + t];
        zq_out[(size_t)row * DIM + t] = z + (q - z);
        float d = q - z;
        lsum += d * d;
        if (k != kprev) {
            atomicAdd(&dw[(size_t)kprev * DIM + t], acc);
            acc = 0.0f;
            kprev = k;
        }
        acc += z;
    }
    atomicAdd(&dw[(size_t)kprev * DIM + t], acc);

    __shared__ float red[256];
    red[t] = lsum;
    __syncthreads();
    for (int s = 128; s; s >>= 1) {
        if (t < s) red[t] += red[t + s];
        __syncthreads();
    }
    if (t == 0) atomicAdd(&loss_part[blockIdx.x & 255], red[0]);
}

// ---------------- per-cluster EMA, n, perplexity, loss ----------------------
__global__ __launch_bounds__(1024) void finalize_cluster(
        const float* __restrict__ ema_cs, const int* __restrict__ counts,
        const float* __restrict__ loss_part, float* __restrict__ out,
        float* __restrict__ n_ws) {
    __shared__ float s1[1024];
    __shared__ float s2[1024];
    __shared__ float s3[1024];
    int t = threadIdx.x;
    float c = (float)counts[t];
    float ncs = DECAY * ema_cs[t] + (1.0f - DECAY) * c;
    out[O_NCS + t] = ncs;
    float p = c / (float)BATCH;
    s1[t] = ncs;
    s2[t] = p * logf(p + 1e-10f);
    s3[t] = (t < 256) ? loss_part[t] : 0.0f;
    __syncthreads();
    for (int s = 512; s; s >>= 1) {
        if (t < s) { s1[t] += s1[t + s]; s2[t] += s2[t + s]; s3[t] += s3[t + s]; }
        __syncthreads();
    }
    if (t == 0) {
        n_ws[0] = s1[0];
        out[O_PERP] = expf(-s2[0]);
        out[O_LOSS] = COMMIT * s3[0] / (float)((size_t)BATCH * DIM);
    }
}

// ---------------- new_ema_w and new_embedding -------------------------------
__global__ __launch_bounds__(256) void finalize_emb(
        const float* __restrict__ ema_w, const float* __restrict__ dw,
        const float* __restrict__ ncs_arr, const float* __restrict__ n_ws,
        float* __restrict__ out_emb, float* __restrict__ out_emaw) {
    int k = blockIdx.x;
    int d = threadIdx.x;
    size_t i = (size_t)k * DIM + d;
    float w = DECAY * ema_w[i] + (1.0f - DECAY) * dw[i];
    out_emaw[i] = w;
    float n = n_ws[0];
    float ncs = ncs_arr[k];
    float smoothed = (ncs + EPSV) / (n + (float)KC * EPSV) * n;
    out_emb[i] = w / smoothed;
}

extern "C" void kernel_launch(void* const* d_in, const int* in_sizes, int n_in,
                              void* d_out, int out_size, void* d_ws, size_t ws_size,
                              hipStream_t stream) {
    const float* z_e    = (const float*)d_in[0];
    const float* emb    = (const float*)d_in[1];
    const float* ema_cs = (const float*)d_in[2];
    const float* ema_w  = (const float*)d_in[3];
    float* out = (float*)d_out;
    float* ws = (float*)d_ws;

    // workspace layout (16B-aligned chunks first)
    float* dw            = ws;                                   // 262144 f
    unsigned short* ehi  = (unsigned short*)(dw + KC * DIM);     // 262144 us
    unsigned short* elo  = ehi + KC * DIM;                       // 262144 us
    float* e_sq          = (float*)(elo + KC * DIM);             // 1024 f
    int* idx             = (int*)(e_sq + KC);                    // 65536 i
    int* counts          = idx + BATCH;                          // 1024 i
    int* cursor          = counts + KC;                          // 1024 i
    int* sorted_rows     = cursor + KC;                          // 65536 i
    float* loss_part     = (float*)(sorted_rows + BATCH);        // 256 f
    float* n_ws          = loss_part + 256;                      // 1 f

    zero_kernel<<<dim3(1024), dim3(256), 0, stream>>>(dw, counts, loss_part);
    prep_kernel<<<dim3(KC), dim3(64), 0, stream>>>(emb, ehi, elo, e_sq);
    argmin_kernel<<<dim3(BATCH / 128), dim3(256), 0, stream>>>(
        z_e, ehi, elo, e_sq, idx, out + O_IDX);
    hist_kernel<<<dim3(128), dim3(256), 0, stream>>>(idx, counts);
    prefix_kernel<<<dim3(1), dim3(1024), 0, stream>>>(counts, cursor);
    scatter_rows_kernel<<<dim3(BATCH / 256), dim3(256), 0, stream>>>(
        idx, cursor, sorted_rows);
    dw_zq_kernel<<<dim3(BATCH / SEG), dim3(256), 0, stream>>>(
        z_e, emb, idx, sorted_rows, out + O_ZQ, dw, loss_part);
    finalize_cluster<<<dim3(1), dim3(1024), 0, stream>>>(
        ema_cs, counts, loss_part, out, n_ws);
    finalize_emb<<<dim3(KC), dim3(256), 0, stream>>>(
        ema_w, dw, out + O_NCS, n_ws, out + O_EMB, out + O_NEW);
}